// Round 6
// baseline (461.325 us; speedup 1.0000x reference)
//
#include <hip/hip_runtime.h>
#include <hip/hip_bf16.h>
#include <stdint.h>

// Problem constants
#define B_   1024
#define L_   50
#define D_   128
#define NV_  8
#define NH_  16
#define KFC  1824   // NV*D + NH*L

typedef __bf16 bf16x8 __attribute__((ext_vector_type(8)));
typedef float  f32x4  __attribute__((ext_vector_type(4)));

static __device__ __forceinline__ bf16x8 as_bf16x8(uint4 u) {
  return __builtin_bit_cast(bf16x8, u);
}

// round-to-nearest-even f32 -> bf16 bits
static __device__ __forceinline__ unsigned short f2b(float x) {
  unsigned u = __float_as_uint(x);
  return (unsigned short)((u + 0x7FFFu + ((u >> 16) & 1u)) >> 16);
}

// ---- workspace layout (bytes) ----
// [0, OV)              : o buffer, B x 1824 f32 (o_v | o_h interleaved), memset 0
// [EOFF, EOFF+ESZ)     : E bf16, [b][ks(4)][204 granules x 16B] (200 data + 4 zero pad)
// [W2OFF, W2OFF+W2SZ)  : repacked conv weights: [pair p=T(i)+j][ks(4)][64 lanes x 16B]
#define OV_BYTES  ((size_t)B_ * KFC * 4)                  //  7,471,104
#define EOFF      (OV_BYTES)
#define EBKS      3264                                    // bytes per (b,ks)
#define ESZ       ((size_t)B_ * 4 * EBKS)                 // 13,369,344
#define W2OFF     (EOFF + ESZ)
#define W2SZ      ((size_t)1275 * 4096)                   //  5,222,400
#define NEED_FULL (W2OFF + W2SZ)                          // 26,062,848

// ======================= kernel P: P_u copy -> out[:, 128:256]
__global__ void ck_kP(const int* __restrict__ uids, const float* __restrict__ uemb,
                      float* __restrict__ out) {
  int b = blockIdx.x, d = threadIdx.x;  // 128 threads
  out[(size_t)b * 256 + 128 + d] = uemb[(size_t)uids[b] * D_ + d];
}

// degenerate fallback (only if ws too small)
__global__ void ck_kZ(float* __restrict__ out) {
  int i = blockIdx.x * 256 + threadIdx.x;
  int b = i >> 7, d = i & 127;
  out[(size_t)b * 256 + d] = 0.f;
}

// ======================= kernel AB: gather E (f32 LDS) -> {bf16 E global, o_v}
__global__ void ck_kAB(const int* __restrict__ item_seq, const float* __restrict__ item_emb,
                       const float* __restrict__ vf, char* __restrict__ ws) {
  int b = blockIdx.x, tid = threadIdx.x;
  __shared__ float E[L_][D_];
  __shared__ float VF[L_][NV_];
  __shared__ int sidx[L_];
  if (tid < L_) sidx[tid] = item_seq[b * L_ + tid];
  for (int c = tid; c < L_ * NV_; c += 256) VF[c / NV_][c % NV_] = vf[c];
  __syncthreads();
  for (int c = tid; c < 1600; c += 256) {   // 50 rows x 32 float4
    int l = c >> 5, ch = c & 31;
    *(float4*)&E[l][ch * 4] = *(const float4*)(item_emb + (size_t)sidx[l] * D_ + ch * 4);
  }
  __syncthreads();
  // (a) bf16 E in padded-204-granule layout
  char* eg = ws + EOFF + (size_t)b * 4 * EBKS;
  #pragma unroll
  for (int it = 0; it < 4; ++it) {
    int c = it * 256 + tid;                 // 0..1023; need 816
    if (c < 816) {
      int ks = c / 204, rem = c - ks * 204;
      uint4 v = make_uint4(0, 0, 0, 0);
      if (rem < 200) {
        int row = rem >> 2, g4 = rem & 3;
        float4 f0 = *(const float4*)&E[row][ks * 32 + g4 * 8];
        float4 f1 = *(const float4*)&E[row][ks * 32 + g4 * 8 + 4];
        v.x = f2b(f0.x) | ((unsigned)f2b(f0.y) << 16);
        v.y = f2b(f0.z) | ((unsigned)f2b(f0.w) << 16);
        v.z = f2b(f1.x) | ((unsigned)f2b(f1.y) << 16);
        v.w = f2b(f1.z) | ((unsigned)f2b(f1.w) << 16);
      }
      *(uint4*)(eg + (size_t)ks * EBKS + rem * 16) = v;
    }
  }
  // (b) o_v
  int d = tid & 127, half = tid >> 7;
  float acc[4] = {0.f, 0.f, 0.f, 0.f};
  for (int l = 0; l < L_; ++l) {
    float e = E[l][d];
    #pragma unroll
    for (int vv = 0; vv < 4; ++vv) acc[vv] += e * VF[l][half * 4 + vv];
  }
  float* o = (float*)ws + (size_t)b * KFC;
  #pragma unroll
  for (int vv = 0; vv < 4; ++vv) o[(half * 4 + vv) * D_ + d] = acc[vv];
}

// ======================= kernel W2: repack hconv_w -> B-frag-ready bf16
__global__ void ck_kW2(const float* __restrict__ hw, char* __restrict__ ws) {
  int p = blockIdx.x, tid = threadIdx.x;     // 1275 blocks x 256
  int ks = tid >> 6, l = tid & 63;
  int n = l & 15, gq = l >> 4;
  int i = (int)((sqrtf(8.0f * (float)p + 1.0f) - 1.0f) * 0.5f);
  while ((i + 1) * (i + 2) / 2 <= p) ++i;
  while (i * (i + 1) / 2 > p) --i;
  int j = p - i * (i + 1) / 2;
  const float* src = hw + ((size_t)(i * 16 + n) * 50 + j) * 128 + ks * 32 + gq * 8;
  float4 f0 = *(const float4*)(src);
  float4 f1 = *(const float4*)(src + 4);
  uint4 v;
  v.x = f2b(f0.x) | ((unsigned)f2b(f0.y) << 16);
  v.y = f2b(f0.z) | ((unsigned)f2b(f0.w) << 16);
  v.z = f2b(f1.x) | ((unsigned)f2b(f1.y) << 16);
  v.w = f2b(f1.z) | ((unsigned)f2b(f1.w) << 16);
  *(uint4*)(ws + W2OFF + (size_t)p * 4096 + tid * 16) = v;
}

// ======================= kernel C5: horizontal convs, M=batch, sliding window of 8
// Grid (64 bx, 12 by), 512 threads; 96 slots x 2 rounds; 3 blocks/CU (LDS 53728).
#define EB_STRIDE 3264
#define LDS_E     (16 * EB_STRIDE)       // 52224
#define NWIN      182
#define WCOST_OFF LDS_E                  // 182 ints (728B, pad 736)
#define SCHED_OFF (LDS_E + 736)          // 96 slots x 2 rounds = 192 ints
#define LDS_TOT   (LDS_E + 736 + 768)    // 53728

#define MFMA_BF16 __builtin_amdgcn_mfma_f32_16x16x32_bf16

template<int NT4>
__device__ __forceinline__ void proc_item(const char* lds, const char* bp0,
    int i, int t0, f32x4 (&acc)[8], int aoff) {
  bf16x8 win[8];
  #pragma unroll
  for (int q = 0; q < 8; ++q) {
    int s = t0 + q; s = s > 50 ? 50 : s;
    win[q] = as_bf16x8(*(const uint4*)(lds + aoff + s * 64));
  }
  uint4 breg[8];
  #pragma unroll
  for (int u = 0; u < 8; ++u)
    breg[u] = *(const uint4*)(bp0 + (size_t)(u <= i ? u : 0) * 4096);

  for (int j0 = 0; j0 <= i; j0 += 8) {
    #pragma unroll
    for (int u = 0; u < 8; ++u) {
      int j = j0 + u;
      if (j <= i) {
        bf16x8 bfr = as_bf16x8(breg[u]);
        acc[0] = MFMA_BF16(win[u], bfr, acc[0], 0, 0, 0);
        acc[1] = MFMA_BF16(win[(u + 1) & 7], bfr, acc[1], 0, 0, 0);
        acc[2] = MFMA_BF16(win[(u + 2) & 7], bfr, acc[2], 0, 0, 0);
        acc[3] = MFMA_BF16(win[(u + 3) & 7], bfr, acc[3], 0, 0, 0);
        int sn = t0 + j + 8; sn = sn > 50 ? 50 : sn;   // row 50 = zero pad row
        win[u] = as_bf16x8(*(const uint4*)(lds + aoff + sn * 64));  // slide
        if (NT4 == 8) {
          acc[4] = MFMA_BF16(win[(u + 4) & 7], bfr, acc[4], 0, 0, 0);
          acc[5] = MFMA_BF16(win[(u + 5) & 7], bfr, acc[5], 0, 0, 0);
          acc[6] = MFMA_BF16(win[(u + 6) & 7], bfr, acc[6], 0, 0, 0);
          acc[7] = MFMA_BF16(win[(u + 7) & 7], bfr, acc[7], 0, 0, 0);
        }
        if (j + 8 <= i) breg[u] = *(const uint4*)(bp0 + (size_t)(j + 8) * 4096);
      }
    }
  }
}

__device__ __forceinline__ void run_item(const char* lds, const char* W2, int ks,
    int enc, f32x4 (&acc)[8], int aoff, int lane) {
  int i = enc & 0xff, t0 = (enc >> 8) & 0xff, nt4 = (enc >> 24) & 0xff;
  const char* bp0 = W2 + (size_t)(i * (i + 1) / 2) * 4096 + ks * 1024 + lane * 16;
  if (nt4 == 4) proc_item<4>(lds, bp0, i, t0, acc, aoff);
  else          proc_item<8>(lds, bp0, i, t0, acc, aoff);
}

__device__ __forceinline__ void epi_item(float* o, const float* hb, int b0,
    int enc, f32x4 (&acc)[8], int lane) {
  int i = enc & 0xff, nt = (enc >> 16) & 0xff;
  int r = lane & 15, gq = lane >> 4;
  float bias = hb[i * 16 + r];
  #pragma unroll
  for (int e = 0; e < 4; ++e) {
    float m = 0.f;
    #pragma unroll
    for (int tt = 0; tt < 8; ++tt)
      if (tt < nt) m = fmaxf(m, fmaxf(acc[tt][e] + bias, 0.f));
    atomicMax((unsigned*)&o[(size_t)(b0 + gq * 4 + e) * KFC + 1024 + i * 16 + r],
              __float_as_uint(m));
  }
}

__launch_bounds__(512, 6)
__global__ void ck_kC5(const float* __restrict__ hconv_b, char* __restrict__ ws) {
  __shared__ char lds[LDS_TOT];
  int* wcost = (int*)(lds + WCOST_OFF);
  int* sched = (int*)(lds + SCHED_OFF);   // 96 slots x 2 rounds
  int tid = threadIdx.x;
  int wv = tid >> 6, lane = tid & 63;
  int r = lane & 15, gq = lane >> 4;
  int b0 = (int)blockIdx.x * 16;
  int slot = (int)blockIdx.y * 8 + wv;
  int aoff = r * EB_STRIDE + gq * 16;

  // ---- snake schedule: 182 windows (t-blocks of 8) ranked by cost ----
  if (tid < 192) sched[tid] = -1;
  int myenc = -1;
  if (tid < NWIN) {
    int idx = tid, i, nw = 1;
    for (i = 0; i < 50; ++i) {
      nw = (57 - i) >> 3;                  // ceil((50-i)/8)
      if (idx < nw) break;
      idx -= nw;
    }
    int ntb = 50 - i - 8 * (nw - 1);
    int nt = idx ? 8 : ntb;
    int t0 = idx ? ntb + 8 * (idx - 1) : 0;
    int nt4 = (nt + 3) & ~3;
    myenc = i | (t0 << 8) | (nt << 16) | (nt4 << 24);
    wcost[tid] = (((i + 1) * nt4) << 8) + tid;   // unique keys
  }
  __syncthreads();
  if (tid < NWIN) {
    int c = wcost[tid], rank = 0;
    for (int u = 0; u < NWIN; ++u) rank += (wcost[u] > c) ? 1 : 0;
    int rnd = rank >= 96 ? 1 : 0;
    int pos = rank - 96 * rnd;
    int sl = rnd ? (95 - pos) : pos;             // snake: balance the 2 rounds
    sched[sl * 2 + rnd] = myenc;
  }
  __syncthreads();

  const char* EG = ws + EOFF;
  const char* W2 = ws + W2OFF;
  float* o = (float*)ws;

  for (int rd = 0; rd < 2; ++rd) {
    int enc = sched[slot * 2 + rd];
    f32x4 acc[8];
    #pragma unroll
    for (int t = 0; t < 8; ++t) {
      acc[t][0] = 0.f; acc[t][1] = 0.f; acc[t][2] = 0.f; acc[t][3] = 0.f;
    }
    for (int ks = 0; ks < 4; ++ks) {
      __syncthreads();
      // stage E d-quarter: 3264 granules of 16B, linear in LDS (conflict-free)
      #pragma unroll
      for (int it = 0; it < 6; ++it) {
        int g = it * 512 + tid;
        int bb = g / 204, off = g - bb * 204;
        *(uint4*)(lds + g * 16) =
          *(const uint4*)(EG + ((size_t)((b0 + bb) * 4 + ks)) * EBKS + off * 16);
      }
      if (tid < 192) {
        int g = 3072 + tid;
        int bb = g / 204, off = g - bb * 204;
        *(uint4*)(lds + g * 16) =
          *(const uint4*)(EG + ((size_t)((b0 + bb) * 4 + ks)) * EBKS + off * 16);
      }
      __syncthreads();
      if (enc >= 0) run_item(lds, W2, ks, enc, acc, aoff, lane);
    }
    if (enc >= 0) epi_item(o, hconv_b, b0, enc, acc, lane);
  }
}

// ======================= kernel D: FC (full K, 2 ksteps/phase) + bias + relu
__launch_bounds__(256)
__global__ void ck_kD(const float* __restrict__ fc_w, const float* __restrict__ fc_b,
                      const char* __restrict__ ws, float* __restrict__ out) {
  __shared__ char ldsD[10240];  // A0@0 A1@4096 (4KB each); B0@8192 B1@9216 (1KB each)
  int b0 = blockIdx.x * 64, n0 = blockIdx.y * 16;
  int tid = threadIdx.x, w = tid >> 6, lane = tid & 63, r = lane & 15, gq = lane >> 4;
  const float* o = (const float*)ws;

  f32x4 acc; acc[0] = 0.f; acc[1] = 0.f; acc[2] = 0.f; acc[3] = 0.f;

  int rl = tid >> 2, ch = tid & 3;
  const float* asrc = o + (size_t)(b0 + rl) * KFC + ch * 8;
  int kk = tid >> 3, nn = tid & 7;

  float4 fa[4]; float fb[4];
  fa[0] = *(const float4*)(asrc);
  fa[1] = *(const float4*)(asrc + 4);
  fa[2] = *(const float4*)(asrc + 32);
  fa[3] = *(const float4*)(asrc + 36);
  fb[0] = fc_w[(size_t)kk * D_ + n0 + nn];
  fb[1] = fc_w[(size_t)kk * D_ + n0 + nn + 8];
  fb[2] = fc_w[(size_t)(32 + kk) * D_ + n0 + nn];
  fb[3] = fc_w[(size_t)(32 + kk) * D_ + n0 + nn + 8];

  int arow_off = rl * 64 + ((ch ^ (rl & 3)) << 4);
  int rloc = w * 16 + r;
  int ard = rloc * 64 + ((gq ^ (rloc & 3)) << 4);
  int brd = 8192 + r * 64 + ((gq ^ (r & 3)) << 4);
  int bw0 = 8192 + nn * 64 + (((kk >> 3) ^ (nn & 3)) << 4) + (kk & 7) * 2;
  int bw1 = 8192 + (nn + 8) * 64 + (((kk >> 3) ^ ((nn + 8) & 3)) << 4) + (kk & 7) * 2;

  for (int s = 0; s < 29; ++s) {
    int k1ok = (2 * s + 1) < 57;
    __syncthreads();
    #pragma unroll
    for (int sl = 0; sl < 2; ++sl) {
      uint4 v;
      v.x = f2b(fa[2*sl].x) | ((unsigned)f2b(fa[2*sl].y) << 16);
      v.y = f2b(fa[2*sl].z) | ((unsigned)f2b(fa[2*sl].w) << 16);
      v.z = f2b(fa[2*sl+1].x) | ((unsigned)f2b(fa[2*sl+1].y) << 16);
      v.w = f2b(fa[2*sl+1].z) | ((unsigned)f2b(fa[2*sl+1].w) << 16);
      *(uint4*)(ldsD + sl * 4096 + arow_off) = v;
      *(unsigned short*)(ldsD + sl * 1024 + bw0) = f2b(fb[2*sl]);
      *(unsigned short*)(ldsD + sl * 1024 + bw1) = f2b(fb[2*sl+1]);
    }
    __syncthreads();
    int kn0 = (2 * s + 2) * 32, kn1 = (2 * s + 3) * 32;
    if (kn0 < 1824) {
      fa[0] = *(const float4*)(asrc + kn0);
      fa[1] = *(const float4*)(asrc + kn0 + 4);
      fb[0] = fc_w[(size_t)(kn0 + kk) * D_ + n0 + nn];
      fb[1] = fc_w[(size_t)(kn0 + kk) * D_ + n0 + nn + 8];
    }
    if (kn1 < 1824) {
      fa[2] = *(const float4*)(asrc + kn1);
      fa[3] = *(const float4*)(asrc + kn1 + 4);
      fb[2] = fc_w[(size_t)(kn1 + kk) * D_ + n0 + nn];
      fb[3] = fc_w[(size_t)(kn1 + kk) * D_ + n0 + nn + 8];
    }
    bf16x8 a0  = as_bf16x8(*(const uint4*)(ldsD + ard));
    bf16x8 b0f = as_bf16x8(*(const uint4*)(ldsD + brd));
    acc = __builtin_amdgcn_mfma_f32_16x16x32_bf16(a0, b0f, acc, 0, 0, 0);
    if (k1ok) {
      bf16x8 a1  = as_bf16x8(*(const uint4*)(ldsD + 4096 + ard));
      bf16x8 b1f = as_bf16x8(*(const uint4*)(ldsD + 1024 + brd));
      acc = __builtin_amdgcn_mfma_f32_16x16x32_bf16(a1, b1f, acc, 0, 0, 0);
    }
  }

  float bias = fc_b[n0 + r];
  #pragma unroll
  for (int e = 0; e < 4; ++e) {
    int row = b0 + w * 16 + gq * 4 + e;
    out[(size_t)row * 256 + n0 + r] = fmaxf(acc[e] + bias, 0.f);
  }
}

extern "C" void kernel_launch(void* const* d_in, const int* in_sizes, int n_in,
                              void* d_out, int out_size, void* d_ws, size_t ws_size,
                              hipStream_t stream) {
  const int*   user_ids = (const int*)d_in[0];
  const int*   item_seq = (const int*)d_in[1];
  const float* user_emb = (const float*)d_in[2];
  const float* item_emb = (const float*)d_in[3];
  const float* vfilter  = (const float*)d_in[4];
  const float* hconv_w  = (const float*)d_in[5];
  const float* hconv_b  = (const float*)d_in[6];
  const float* fc_w     = (const float*)d_in[7];
  const float* fc_b     = (const float*)d_in[8];
  float* out = (float*)d_out;
  char*  ws  = (char*)d_ws;

  ck_kP<<<dim3(B_), dim3(128), 0, stream>>>(user_ids, user_emb, out);

  if (ws_size < NEED_FULL) {
    ck_kZ<<<dim3(512), dim3(256), 0, stream>>>(out);
    return;
  }

  hipMemsetAsync(ws, 0, OV_BYTES, stream);  // atomicMax identity (all outputs >= 0)

  ck_kAB<<<dim3(B_), dim3(256), 0, stream>>>(item_seq, item_emb, vfilter, ws);
  ck_kW2<<<dim3(1275), dim3(256), 0, stream>>>(hconv_w, ws);
  ck_kC5<<<dim3(64, 12), dim3(512), 0, stream>>>(hconv_b, ws);
  ck_kD<<<dim3(16, 8), dim3(256), 0, stream>>>(fc_w, fc_b, ws, out);
}

// Round 7
// 174.858 us; speedup vs baseline: 2.6383x; 2.6383x over previous
//
#include <hip/hip_runtime.h>
#include <hip/hip_bf16.h>
#include <stdint.h>

// Problem constants
#define B_   1024
#define L_   50
#define D_   128
#define NV_  8
#define NH_  16
#define KFC  1824   // NV*D + NH*L

typedef __bf16 bf16x8 __attribute__((ext_vector_type(8)));
typedef float  f32x4  __attribute__((ext_vector_type(4)));

static __device__ __forceinline__ bf16x8 as_bf16x8(uint4 u) {
  return __builtin_bit_cast(bf16x8, u);
}

// round-to-nearest-even f32 -> bf16 bits
static __device__ __forceinline__ unsigned short f2b(float x) {
  unsigned u = __float_as_uint(x);
  return (unsigned short)((u + 0x7FFFu + ((u >> 16) & 1u)) >> 16);
}

// ---- workspace layout (bytes) ----
// [0, OV)              : o buffer, B x 1824 f32 (o_v | o_h), memset 0 each launch
// [E3OFF, +E3SZ)       : E bf16, [ks(4)][bg(64)][row(51)][16 b x 64B]  (row 50 = zeros)
//                        offset = ks*3342336 + bg*52224 + row*1024 + (b&15)*64 + gq*16
// [W2OFF, +W2SZ)       : repacked conv weights: [pair p=T(i)+j][ks(4)][64 lanes x 16B]
#define OV_BYTES  ((size_t)B_ * KFC * 4)                  //  7,471,104
#define E3OFF     (OV_BYTES)
#define E3_KS     3342336                                 // 64 * 52224
#define E3_BG     52224                                   // 51 * 1024
#define E3SZ      ((size_t)4 * E3_KS)                     // 13,369,344
#define W2OFF     (E3OFF + E3SZ)
#define W2SZ      ((size_t)1275 * 4096)                   //  5,222,400
#define NEED_FULL (W2OFF + W2SZ)                          // 26,062,848

// ======================= kernel P: P_u copy -> out[:, 128:256]
__global__ void ck_kP(const int* __restrict__ uids, const float* __restrict__ uemb,
                      float* __restrict__ out) {
  int b = blockIdx.x, d = threadIdx.x;  // 128 threads
  out[(size_t)b * 256 + 128 + d] = uemb[(size_t)uids[b] * D_ + d];
}

// degenerate fallback (only if ws too small)
__global__ void ck_kZ(float* __restrict__ out) {
  int i = blockIdx.x * 256 + threadIdx.x;
  int b = i >> 7, d = i & 127;
  out[(size_t)b * 256 + d] = 0.f;
}

// ======================= kernel AB: gather E (f32 LDS) -> {bf16 E3 global, o_v}
__global__ void ck_kAB(const int* __restrict__ item_seq, const float* __restrict__ item_emb,
                       const float* __restrict__ vf, char* __restrict__ ws) {
  int b = blockIdx.x, tid = threadIdx.x;
  __shared__ float E[L_][D_];
  __shared__ float VF[L_][NV_];
  __shared__ int sidx[L_];
  if (tid < L_) sidx[tid] = item_seq[b * L_ + tid];
  for (int c = tid; c < L_ * NV_; c += 256) VF[c / NV_][c % NV_] = vf[c];
  __syncthreads();
  for (int c = tid; c < 1600; c += 256) {   // 50 rows x 32 float4
    int l = c >> 5, ch = c & 31;
    *(float4*)&E[l][ch * 4] = *(const float4*)(item_emb + (size_t)sidx[l] * D_ + ch * 4);
  }
  __syncthreads();
  // (a) bf16 E3: 4 ks x (50 data rows x 4 granules + 4 zero granules of row 50)
  char* eg = ws + E3OFF + (size_t)(b >> 4) * E3_BG + (b & 15) * 64;
  #pragma unroll
  for (int it = 0; it < 4; ++it) {
    int c = it * 256 + tid;                 // 0..1023; need 816
    if (c < 816) {
      int ks = c / 204, rem = c - ks * 204;
      uint4 v = make_uint4(0, 0, 0, 0);
      int row, gq;
      if (rem < 200) {
        row = rem >> 2; gq = rem & 3;
        float4 f0 = *(const float4*)&E[row][ks * 32 + gq * 8];
        float4 f1 = *(const float4*)&E[row][ks * 32 + gq * 8 + 4];
        v.x = f2b(f0.x) | ((unsigned)f2b(f0.y) << 16);
        v.y = f2b(f0.z) | ((unsigned)f2b(f0.w) << 16);
        v.z = f2b(f1.x) | ((unsigned)f2b(f1.y) << 16);
        v.w = f2b(f1.z) | ((unsigned)f2b(f1.w) << 16);
      } else {
        row = 50; gq = rem - 200;           // zero pad row
      }
      *(uint4*)(eg + (size_t)ks * E3_KS + row * 1024 + gq * 16) = v;
    }
  }
  // (b) o_v
  int d = tid & 127, half = tid >> 7;
  float acc[4] = {0.f, 0.f, 0.f, 0.f};
  for (int l = 0; l < L_; ++l) {
    float e = E[l][d];
    #pragma unroll
    for (int vv = 0; vv < 4; ++vv) acc[vv] += e * VF[l][half * 4 + vv];
  }
  float* o = (float*)ws + (size_t)b * KFC;
  #pragma unroll
  for (int vv = 0; vv < 4; ++vv) o[(half * 4 + vv) * D_ + d] = acc[vv];
}

// ======================= kernel W2: repack hconv_w -> B-frag-ready bf16
__global__ void ck_kW2(const float* __restrict__ hw, char* __restrict__ ws) {
  int p = blockIdx.x, tid = threadIdx.x;     // 1275 blocks x 256
  int ks = tid >> 6, l = tid & 63;
  int n = l & 15, gq = l >> 4;
  int i = (int)((sqrtf(8.0f * (float)p + 1.0f) - 1.0f) * 0.5f);
  while ((i + 1) * (i + 2) / 2 <= p) ++i;
  while (i * (i + 1) / 2 > p) --i;
  int j = p - i * (i + 1) / 2;
  const float* src = hw + ((size_t)(i * 16 + n) * 50 + j) * 128 + ks * 32 + gq * 8;
  float4 f0 = *(const float4*)(src);
  float4 f1 = *(const float4*)(src + 4);
  uint4 v;
  v.x = f2b(f0.x) | ((unsigned)f2b(f0.y) << 16);
  v.y = f2b(f0.z) | ((unsigned)f2b(f0.w) << 16);
  v.z = f2b(f1.x) | ((unsigned)f2b(f1.y) << 16);
  v.w = f2b(f1.z) | ((unsigned)f2b(f1.w) << 16);
  *(uint4*)(ws + W2OFF + (size_t)p * 4096 + tid * 16) = v;
}

// ======================= kernel C6: horizontal convs, pure register streaming
// No LDS, no barriers. One window per wave; E and W2 stream from L2 with
// 8-deep register prefetch. bgroup = bid&63 => bgroup mod 8 == XCD (round-robin)
// so each XCD's L2 holds only its 8 bgroups' E slices (1.6 MB).
#define MFMA_BF16 __builtin_amdgcn_mfma_f32_16x16x32_bf16

template<int NT4>
__device__ __forceinline__ void proc_item_g(const char* __restrict__ ebase,
    const char* __restrict__ bp0, int i, int t0, f32x4 (&acc)[8]) {
  bf16x8 win[8];
  #pragma unroll
  for (int q = 0; q < 8; ++q) {
    int s = t0 + q; s = s > 50 ? 50 : s;      // row 50 = zero pad
    win[q] = as_bf16x8(*(const uint4*)(ebase + s * 1024));
  }
  uint4 breg[8];
  #pragma unroll
  for (int u = 0; u < 8; ++u)
    breg[u] = *(const uint4*)(bp0 + (size_t)(u <= i ? u : 0) * 4096);

  for (int j0 = 0; j0 <= i; j0 += 8) {
    #pragma unroll
    for (int u = 0; u < 8; ++u) {
      int j = j0 + u;
      if (j <= i) {
        bf16x8 bfr = as_bf16x8(breg[u]);
        acc[0] = MFMA_BF16(win[u], bfr, acc[0], 0, 0, 0);
        acc[1] = MFMA_BF16(win[(u + 1) & 7], bfr, acc[1], 0, 0, 0);
        acc[2] = MFMA_BF16(win[(u + 2) & 7], bfr, acc[2], 0, 0, 0);
        acc[3] = MFMA_BF16(win[(u + 3) & 7], bfr, acc[3], 0, 0, 0);
        int sn = t0 + j + 8; sn = sn > 50 ? 50 : sn;
        win[u] = as_bf16x8(*(const uint4*)(ebase + sn * 1024));   // slide (global)
        if (NT4 == 8) {
          acc[4] = MFMA_BF16(win[(u + 4) & 7], bfr, acc[4], 0, 0, 0);
          acc[5] = MFMA_BF16(win[(u + 5) & 7], bfr, acc[5], 0, 0, 0);
          acc[6] = MFMA_BF16(win[(u + 6) & 7], bfr, acc[6], 0, 0, 0);
          acc[7] = MFMA_BF16(win[(u + 7) & 7], bfr, acc[7], 0, 0, 0);
        }
        if (j + 8 <= i) breg[u] = *(const uint4*)(bp0 + (size_t)(j + 8) * 4096);
      }
    }
  }
}

__launch_bounds__(256, 4)
__global__ void ck_kC6(const float* __restrict__ hconv_b, char* __restrict__ ws) {
  int tid = threadIdx.x;
  int wv = tid >> 6, lane = tid & 63;
  int r = lane & 15, gq = lane >> 4;
  int bid = (int)blockIdx.x;
  int g = bid & 63;                  // bgroup; g mod 8 tracks XCD under round-robin
  int q = bid >> 6;                  // window quad 0..45
  int widx = q * 4 + wv;             // 0..183 (182,183 idle)

  // decode widx -> (i, t0, nt, nt4), windows ordered by descending i
  int rem = widx, i = -1, nt = 0, t0 = 0;
  for (int ii = 49; ii >= 0; --ii) {
    int nw = (57 - ii) >> 3;         // ceil((50-ii)/8)
    if (rem < nw) {
      i = ii;
      int ntb = 50 - ii - 8 * (nw - 1);
      nt = rem ? 8 : ntb;
      t0 = rem ? ntb + 8 * (rem - 1) : 0;
      break;
    }
    rem -= nw;
  }
  if (i < 0) return;                 // idle wave (no barriers in this kernel)
  int nt4 = (nt + 3) & ~3;

  const char* EG = ws + E3OFF + (size_t)g * E3_BG + r * 64 + gq * 16;
  const char* W2 = ws + W2OFF + (size_t)(i * (i + 1) / 2) * 4096 + lane * 16;
  float* o = (float*)ws;

  f32x4 acc[8];
  #pragma unroll
  for (int t = 0; t < 8; ++t) {
    acc[t][0] = 0.f; acc[t][1] = 0.f; acc[t][2] = 0.f; acc[t][3] = 0.f;
  }

  #pragma unroll
  for (int ks = 0; ks < 4; ++ks) {
    const char* ebase = EG + (size_t)ks * E3_KS;
    const char* bp0   = W2 + ks * 1024;
    if (nt4 == 4) proc_item_g<4>(ebase, bp0, i, t0, acc);
    else          proc_item_g<8>(ebase, bp0, i, t0, acc);
  }

  // epilogue: bias + relu + masked max over t, atomicMax into o
  int b0 = g * 16;
  float bias = hconv_b[i * 16 + r];
  #pragma unroll
  for (int e = 0; e < 4; ++e) {
    float m = 0.f;
    #pragma unroll
    for (int tt = 0; tt < 8; ++tt)
      if (tt < nt) m = fmaxf(m, fmaxf(acc[tt][e] + bias, 0.f));
    atomicMax((unsigned*)&o[(size_t)(b0 + gq * 4 + e) * KFC + 1024 + i * 16 + r],
              __float_as_uint(m));
  }
}

// ======================= kernel D: FC (full K, 2 ksteps/phase) + bias + relu
__launch_bounds__(256)
__global__ void ck_kD(const float* __restrict__ fc_w, const float* __restrict__ fc_b,
                      const char* __restrict__ ws, float* __restrict__ out) {
  __shared__ char ldsD[10240];  // A0@0 A1@4096 (4KB each); B0@8192 B1@9216 (1KB each)
  int b0 = blockIdx.x * 64, n0 = blockIdx.y * 16;
  int tid = threadIdx.x, w = tid >> 6, lane = tid & 63, r = lane & 15, gq = lane >> 4;
  const float* o = (const float*)ws;

  f32x4 acc; acc[0] = 0.f; acc[1] = 0.f; acc[2] = 0.f; acc[3] = 0.f;

  int rl = tid >> 2, ch = tid & 3;
  const float* asrc = o + (size_t)(b0 + rl) * KFC + ch * 8;
  int kk = tid >> 3, nn = tid & 7;

  float4 fa[4]; float fb[4];
  fa[0] = *(const float4*)(asrc);
  fa[1] = *(const float4*)(asrc + 4);
  fa[2] = *(const float4*)(asrc + 32);
  fa[3] = *(const float4*)(asrc + 36);
  fb[0] = fc_w[(size_t)kk * D_ + n0 + nn];
  fb[1] = fc_w[(size_t)kk * D_ + n0 + nn + 8];
  fb[2] = fc_w[(size_t)(32 + kk) * D_ + n0 + nn];
  fb[3] = fc_w[(size_t)(32 + kk) * D_ + n0 + nn + 8];

  int arow_off = rl * 64 + ((ch ^ (rl & 3)) << 4);
  int rloc = w * 16 + r;
  int ard = rloc * 64 + ((gq ^ (rloc & 3)) << 4);
  int brd = 8192 + r * 64 + ((gq ^ (r & 3)) << 4);
  int bw0 = 8192 + nn * 64 + (((kk >> 3) ^ (nn & 3)) << 4) + (kk & 7) * 2;
  int bw1 = 8192 + (nn + 8) * 64 + (((kk >> 3) ^ ((nn + 8) & 3)) << 4) + (kk & 7) * 2;

  for (int s = 0; s < 29; ++s) {
    int k1ok = (2 * s + 1) < 57;
    __syncthreads();
    #pragma unroll
    for (int sl = 0; sl < 2; ++sl) {
      uint4 v;
      v.x = f2b(fa[2*sl].x) | ((unsigned)f2b(fa[2*sl].y) << 16);
      v.y = f2b(fa[2*sl].z) | ((unsigned)f2b(fa[2*sl].w) << 16);
      v.z = f2b(fa[2*sl+1].x) | ((unsigned)f2b(fa[2*sl+1].y) << 16);
      v.w = f2b(fa[2*sl+1].z) | ((unsigned)f2b(fa[2*sl+1].w) << 16);
      *(uint4*)(ldsD + sl * 4096 + arow_off) = v;
      *(unsigned short*)(ldsD + sl * 1024 + bw0) = f2b(fb[2*sl]);
      *(unsigned short*)(ldsD + sl * 1024 + bw1) = f2b(fb[2*sl+1]);
    }
    __syncthreads();
    int kn0 = (2 * s + 2) * 32, kn1 = (2 * s + 3) * 32;
    if (kn0 < 1824) {
      fa[0] = *(const float4*)(asrc + kn0);
      fa[1] = *(const float4*)(asrc + kn0 + 4);
      fb[0] = fc_w[(size_t)(kn0 + kk) * D_ + n0 + nn];
      fb[1] = fc_w[(size_t)(kn0 + kk) * D_ + n0 + nn + 8];
    }
    if (kn1 < 1824) {
      fa[2] = *(const float4*)(asrc + kn1);
      fa[3] = *(const float4*)(asrc + kn1 + 4);
      fb[2] = fc_w[(size_t)(kn1 + kk) * D_ + n0 + nn];
      fb[3] = fc_w[(size_t)(kn1 + kk) * D_ + n0 + nn + 8];
    }
    bf16x8 a0  = as_bf16x8(*(const uint4*)(ldsD + ard));
    bf16x8 b0f = as_bf16x8(*(const uint4*)(ldsD + brd));
    acc = __builtin_amdgcn_mfma_f32_16x16x32_bf16(a0, b0f, acc, 0, 0, 0);
    if (k1ok) {
      bf16x8 a1  = as_bf16x8(*(const uint4*)(ldsD + 4096 + ard));
      bf16x8 b1f = as_bf16x8(*(const uint4*)(ldsD + 1024 + brd));
      acc = __builtin_amdgcn_mfma_f32_16x16x32_bf16(a1, b1f, acc, 0, 0, 0);
    }
  }

  float bias = fc_b[n0 + r];
  #pragma unroll
  for (int e = 0; e < 4; ++e) {
    int row = b0 + w * 16 + gq * 4 + e;
    out[(size_t)row * 256 + n0 + r] = fmaxf(acc[e] + bias, 0.f);
  }
}

extern "C" void kernel_launch(void* const* d_in, const int* in_sizes, int n_in,
                              void* d_out, int out_size, void* d_ws, size_t ws_size,
                              hipStream_t stream) {
  const int*   user_ids = (const int*)d_in[0];
  const int*   item_seq = (const int*)d_in[1];
  const float* user_emb = (const float*)d_in[2];
  const float* item_emb = (const float*)d_in[3];
  const float* vfilter  = (const float*)d_in[4];
  const float* hconv_w  = (const float*)d_in[5];
  const float* hconv_b  = (const float*)d_in[6];
  const float* fc_w     = (const float*)d_in[7];
  const float* fc_b     = (const float*)d_in[8];
  float* out = (float*)d_out;
  char*  ws  = (char*)d_ws;

  ck_kP<<<dim3(B_), dim3(128), 0, stream>>>(user_ids, user_emb, out);

  if (ws_size < NEED_FULL) {
    ck_kZ<<<dim3(512), dim3(256), 0, stream>>>(out);
    return;
  }

  hipMemsetAsync(ws, 0, OV_BYTES, stream);  // atomicMax identity (all outputs >= 0)

  ck_kAB<<<dim3(B_), dim3(256), 0, stream>>>(item_seq, item_emb, vfilter, ws);
  ck_kW2<<<dim3(1275), dim3(256), 0, stream>>>(hconv_w, ws);
  ck_kC6<<<dim3(2944), dim3(256), 0, stream>>>(hconv_b, ws);
  ck_kD<<<dim3(16, 8), dim3(256), 0, stream>>>(fc_w, fc_b, ws, out);
}